// Round 5
// baseline (10433.361 us; speedup 1.0000x reference)
//
#include <hip/hip_runtime.h>

// Decoder GRU, B=128 T=512 X=64 H=256, skip runtime (skip==0 -> generic
// path).  Round 11: NT=256 full-residency persistent RNN.
//
// R10 post-mortem: at NT=512 (8 waves) the per-lane reg budget is 256 -> the
// 192-reg W_hh array can't be resident (VGPR_Count stayed 128; part went to
// AGPR/scratch, re-read every step -> 5200 cyc/step vs ~1100 floor).
// At NT=256 (4 waves, 1/SIMD) the budget is 512 regs/lane: W_hh fp16 =
// 384 regs/thread fits ENTIRELY, pinned 40 uint4 "+v" + 56 uint4 "+a"
// (gfx950 VALU reads AGPRs directly).  VALU floor is unchanged (issue is
// per-SIMD: 262k MACs/step / 256 MACs/cyc/CU ~= 1024 cyc).
// Each thread owns one H-column: full K=256 in-thread, 3 gates -> NO
// shuffle reduces in GATES; h is a wave-uniform LDS broadcast.
// W_ih (96 KB) + W_out (32 KB) in LDS [u][t] (lane-consecutive 16 B).
// pt2 in 4 K-blocks of 36-word stride -> PROJ's 4 sl-groups hit disjoint
// bank quads.  Single barrier per main-loop step (R7/R10 verified math).
// LDS ~150 KB; per-step global traffic: 256 B out-write only.
typedef _Float16 h2_t __attribute__((ext_vector_type(2)));

constexpr int T_ = 512;
constexpr int X_ = 64;
constexpr int H_ = 256;
constexpr int NWG = 128;  // 1 batch per WG, 1 WG/CU
constexpr int NT = 256;   // 4 waves, 1/SIMD -> 512 regs/lane budget
constexpr int RS = 16;    // ring slots; lookback 2*skip, OK for skip <= 7

// fp16 weight images in d_ws (uint4 units)
constexpr int GHH_U4 = 96 * 256;  // [u=g*32+j][c]  W_hh rows, K-contiguous
constexpr int GIH_U4 = 24 * 256;  // [u=g*8+j][t]
constexpr int GOUT_U4 = 8 * 256;  // [j][t]  (t = xc*4+sl)
constexpr int G_TOTAL = GHH_U4 + GIH_U4 + GOUT_U4;  // 32768 u4 = 512 KB

__device__ __forceinline__ float sigmoid_f(float x) {
  float e = __expf(fminf(-x, 80.f));
  return 1.f / (1.f + e);
}
__device__ __forceinline__ float tanh_f(float x) {
  float e = __expf(fminf(-2.f * x, 80.f));
  return (1.f - e) / (1.f + e);
}

__device__ __forceinline__ unsigned pk2(float a, float b) {
  h2_t v;
  v[0] = (_Float16)a;
  v[1] = (_Float16)b;
  return __builtin_bit_cast(unsigned, v);
}
__device__ __forceinline__ uint4 pk8(const float* s) {
  return make_uint4(pk2(s[0], s[1]), pk2(s[2], s[3]), pk2(s[4], s[5]),
                    pk2(s[6], s[7]));
}

// fp16-pair dot with fp32 accumulate (v_dot2_f32_f16)
__device__ __forceinline__ float dotp(unsigned w, unsigned h, float acc) {
  h2_t wv = __builtin_bit_cast(h2_t, w);
  h2_t hv = __builtin_bit_cast(h2_t, h);
#if __has_builtin(__builtin_amdgcn_fdot2)
  return __builtin_amdgcn_fdot2(wv, hv, acc, false);
#else
  acc = fmaf((float)wv[0], (float)hv[0], acc);
  return fmaf((float)wv[1], (float)hv[1], acc);
#endif
}
__device__ __forceinline__ float dotq(uint4 w, uint4 h, float acc) {
  acc = dotp(w.x, h.x, acc);
  acc = dotp(w.y, h.y, acc);
  acc = dotp(w.z, h.z, acc);
  acc = dotp(w.w, h.w, acc);
  return acc;
}

// One-time fp32 -> fp16 pack + transpose into register/LDS-friendly layouts.
__global__ void prep_kernel(const float* __restrict__ Wih,
                            const float* __restrict__ Whh,
                            const float* __restrict__ Wout,
                            uint4* __restrict__ G) {
  int id = blockIdx.x * 256 + threadIdx.x;
  if (id < GHH_U4) {
    int c = id & 255, u = id >> 8;    // u = g*32 + j
    int g = u >> 5, j = u & 31;
    G[id] = pk8(Whh + (size_t)(g * 256 + c) * H_ + j * 8);
  } else if (id < GHH_U4 + GIH_U4) {
    int jd = id - GHH_U4;
    int tt = jd & 255, u = jd >> 8;   // u = g*8 + j
    int g = u >> 3, j = u & 7;
    G[id] = pk8(Wih + (size_t)(g * 256 + tt) * X_ + j * 8);
  } else if (id < G_TOTAL) {
    int jd = id - GHH_U4 - GIH_U4;    // [j][t]
    int tt = jd & 255, j = jd >> 8;
    int xc = tt >> 2, sl = tt & 3;
    G[id] = pk8(Wout + (size_t)xc * H_ + sl * 64 + j * 8);
  }
}

// pt2 padded word index for col-pair cp (0..127): K-block (cp>>5) stride 36
// words -> PROJ's 4 sl-address-groups start at banks 4*sl (disjoint quads).
#define PTW(cp) (((cp) >> 5) * 36 + ((cp)&31))

// NOTE: parameter name must not collide with .x/.y/.z/.w member names.
#define PIN4V(V4)                                                            \
  asm volatile("" : "+v"((V4).x), "+v"((V4).y), "+v"((V4).z), "+v"((V4).w))
#define PIN4A(V4)                                                            \
  asm volatile("" : "+a"((V4).x), "+a"((V4).y), "+a"((V4).z), "+a"((V4).w))

// ---- per-step building blocks (p/q compile-time 0/1 in the main loop) ----
// Thread t owns H-column c=t: full K=256 per gate in-thread, no reduces.

#define GATES(p, i, hn)                                                      \
  float hn;                                                                  \
  {                                                                          \
    float a0 = 0, a1 = 0, z0 = 0, z1 = 0, n0 = 0, n1 = 0, ni = 0;            \
    const uint4* h4 = (const uint4*)hid2[p];                                 \
    _Pragma("unroll") for (int j = 0; j < 32; j += 2) {                      \
      uint4 ha = h4[j], hb = h4[j + 1]; /* wave-uniform broadcast */         \
      a0 = dotq(whh[j], ha, a0);                                             \
      a1 = dotq(whh[j + 1], hb, a1);                                         \
      z0 = dotq(whh[32 + j], ha, z0);                                        \
      z1 = dotq(whh[33 + j], hb, z1);                                        \
      n0 = dotq(whh[64 + j], ha, n0);                                        \
      n1 = dotq(whh[65 + j], hb, n1);                                        \
    }                                                                        \
    const uint4* x4 = (const uint4*)xt2[p];                                  \
    _Pragma("unroll") for (int j = 0; j < 8; ++j) {                          \
      uint4 xa = x4[j]; /* broadcast */                                      \
      a0 = dotq(wlih[j * NT + t], xa, a0);                                   \
      z0 = dotq(wlih[(8 + j) * NT + t], xa, z0);                             \
      ni = dotq(wlih[(16 + j) * NT + t], xa, ni);                            \
    }                                                                        \
    float r = sigmoid_f(a0 + a1 + bsr);                                      \
    float z = sigmoid_f(z0 + z1 + bsz);                                      \
    float n = tanh_f(ni + bin_ + r * (n0 + n1 + bhn_));                      \
    hn = fmaf(z, hid_reg - n, n); /* (1-z)*n + z*hidden */                   \
    ring[(i) & (RS - 1)][t] = hn;                                            \
  }

#define PROJ(p, q, i)                                                        \
  {                                                                          \
    float fa = 0;                                                            \
    const uint4* p4 = (const uint4*)&pt2[p][sl * 36];                        \
    _Pragma("unroll") for (int j = 0; j < 8; ++j) fa =                       \
        dotq(wout_r[j * NT + t], p4[j], fa);                                 \
    fa += __shfl_xor(fa, 1);                                                 \
    fa += __shfl_xor(fa, 2);                                                 \
    float o = fa + bo;                                                       \
    if (sl == 0) out[ob + (size_t)(i)*X_ + xc] = o;                          \
    float oo = __shfl_xor(o, 4);                                             \
    if ((t & 7) == 0) xt2[q][t >> 3] = pk2(o, oo);                           \
  }

// Main-loop step (valid for i >= 2*skip, skip >= 1): pt2[p] was produced at
// step i-1; sg == sp == h(i+1-2*skip) for the next step's hidden/pt.
#define MSTEP(i, p, q)                                                       \
  {                                                                          \
    GATES(p, i, hn)                                                          \
    __builtin_amdgcn_sched_barrier(0);                                       \
    PROJ(p, q, i)                                                            \
    __builtin_amdgcn_sched_barrier(0);                                       \
    if ((i) + 1 < T_) {                                                      \
      float sgp = ring[((i) + 1 - 2 * skip) & (RS - 1)][t];                  \
      float hidn = m0f[(i) + 1] * hn + m1f[(i) + 1] * sgp;                   \
      float ptn = hn + sgp;                                                  \
      hid_reg = hidn;                                                        \
      float ho = __shfl_xor(hidn, 1);                                        \
      float po = __shfl_xor(ptn, 1);                                         \
      if (!(t & 1)) {                                                        \
        hid2[q][t >> 1] = pk2(hidn, ho);                                     \
        pt2[q][PTW(t >> 1)] = pk2(ptn, po);                                  \
      }                                                                      \
    }                                                                        \
    __syncthreads();                                                         \
  }

__global__ __launch_bounds__(NT, 1) void decoder_kernel(
    const float* __restrict__ h_enc, const float* __restrict__ b_ih,
    const float* __restrict__ b_hh, const float* __restrict__ b_out,
    const int* __restrict__ mask0, const int* __restrict__ mask1,
    const int* __restrict__ skipp, const uint4* __restrict__ G,
    float* __restrict__ out) {
  __shared__ alignas(16) uint4 wlih[24 * NT];      // 96 KB W_ih fp16 [u][t]
  __shared__ alignas(16) uint4 wout_r[8 * NT];     // 32 KB W_out fp16 [j][t]
  __shared__ float ring[RS][H_];                   // 16 KB h history (fp32)
  __shared__ alignas(16) unsigned hid2[2][H_ / 2]; // fp16 hidden pairs
  __shared__ alignas(16) unsigned pt2[2][4 * 36];  // fp16 h_prev+skip, padded
  __shared__ alignas(16) unsigned xt2[2][X_ / 2];  // fp16 x feedback pairs
  __shared__ float m0f[T_], m1f[T_];               // 4 KB masks
  // total ~= 98304+32768+16384+1024+1152+256+4096 = 153984 B (150.4 KB)

  const int t = threadIdx.x;
  const int b = blockIdx.x;
  const int xc = t >> 2, sl = t & 3;  // projection role
  const size_t ob = (size_t)b * T_ * X_;

  // ---- persistent W_hh registers: 96 uint4 = 384 regs, split V/A ----
  uint4 whh[96];
#pragma unroll
  for (int u = 0; u < 96; ++u) whh[u] = G[u * 256 + t];
#pragma unroll
  for (int u = 0; u < 40; ++u) PIN4V(whh[u]);  // 160 arch VGPRs
#pragma unroll
  for (int u = 40; u < 96; ++u) PIN4A(whh[u]);  // 224 AGPRs

  // ---- LDS weight caches ----
#pragma unroll
  for (int u = 0; u < 24; ++u) wlih[u * NT + t] = G[GHH_U4 + u * NT + t];
#pragma unroll
  for (int j = 0; j < 8; ++j)
    wout_r[j * NT + t] = G[GHH_U4 + GIH_U4 + j * NT + t];
  m0f[t] = (float)mask0[t];
  m0f[NT + t] = (float)mask0[NT + t];
  m1f[t] = (float)mask1[t];
  m1f[NT + t] = (float)mask1[NT + t];

  const int skip = skipp[0];
  const int i0 = (skip == 0) ? T_ : ((2 * skip < T_) ? 2 * skip : T_);

  const float bsr = b_ih[t] + b_hh[t];
  const float bsz = b_ih[H_ + t] + b_hh[H_ + t];
  const float bin_ = b_ih[2 * H_ + t];
  const float bhn_ = b_hh[2 * H_ + t];
  const float bo = b_out[xc];

  float hp = h_enc[(size_t)b * H_ + t];
  float hid_reg = (float)mask0[0] * hp;  // hidden(0); skip_g(0) == 0
  float hps_reg = hp;                    // h_prev(0) = h_enc
  {
    float ho = __shfl_xor(hid_reg, 1);
    if (!(t & 1)) hid2[0][t >> 1] = pk2(hid_reg, ho);
  }
  if (t < X_ / 2) xt2[0][t] = 0u;  // GO token
  __syncthreads();

  // ---- prologue: generic 2-barrier steps for i < 2*skip ----
  for (int i = 0; i < i0; ++i) {
    const int p = i & 1, q = p ^ 1;
    GATES(p, i, hn)
    {
      int ppos = (i < skip) ? 2 * i + 1 : i - skip;
      bool pz = ppos < skip;
      int pi = ppos - skip;
      if (pi < 0) pi = 0;
      float sp = pz ? 0.f : ((pi == i) ? hn : ring[pi & (RS - 1)][t]);
      float ptv = hps_reg + sp;
      float po = __shfl_xor(ptv, 1);
      if (!(t & 1)) pt2[p][PTW(t >> 1)] = pk2(ptv, po);
    }
    if (i + 1 < T_) {
      int i1 = i + 1;
      int pg = (i1 < skip) ? 2 * i1 : i1 - skip;
      bool gz = pg < skip;
      int gi = pg - skip;
      if (gi < 0) gi = 0;
      if (gi >= i1) gz = true;  // unwritten slot == reference zero init
      float sg = gz ? 0.f : ((gi == i) ? hn : ring[gi & (RS - 1)][t]);
      float hidn = m0f[i1] * hn + m1f[i1] * sg;
      hid_reg = hidn;
      float ho = __shfl_xor(hidn, 1);
      if (!(t & 1)) hid2[q][t >> 1] = pk2(hidn, ho);
      if (skip > 0 && i1 >= 2 * skip) {  // handoff into fused main loop
        float sgp = ring[(i1 - 2 * skip) & (RS - 1)][t];
        float ptn = hn + sgp;
        float po2 = __shfl_xor(ptn, 1);
        if (!(t & 1)) pt2[q][PTW(t >> 1)] = pk2(ptn, po2);
      }
    }
    hps_reg = hn;
    __syncthreads();
    PROJ(p, q, i)
    __syncthreads();
  }

  // ---- main loop: one barrier per step; i0 even so parity is static ----
#pragma unroll 1
  for (int i = i0; i < T_; i += 2) {
    MSTEP(i, 0, 1)
    MSTEP(i + 1, 1, 0)
  }
}

extern "C" void kernel_launch(void* const* d_in, const int* in_sizes, int n_in,
                              void* d_out, int out_size, void* d_ws,
                              size_t ws_size, hipStream_t stream) {
  (void)in_sizes; (void)n_in; (void)out_size; (void)ws_size;
  // d_in[0] = input [B,T,X] — unused by the reference computation.
  const float* h_enc = (const float*)d_in[1];
  const float* W_ih = (const float*)d_in[2];
  const float* W_hh = (const float*)d_in[3];
  const float* b_ih = (const float*)d_in[4];
  const float* b_hh = (const float*)d_in[5];
  const float* W_out = (const float*)d_in[6];
  const float* b_out = (const float*)d_in[7];
  const int* mask0 = (const int*)d_in[8];
  const int* mask1 = (const int*)d_in[9];
  const int* skipp = (const int*)d_in[10];
  float* out = (float*)d_out;
  uint4* G = (uint4*)d_ws;  // 512 KB fp16 weight images

  prep_kernel<<<dim3(G_TOTAL / 256), dim3(256), 0, stream>>>(W_ih, W_hh,
                                                             W_out, G);
  decoder_kernel<<<dim3(NWG), dim3(NT), 0, stream>>>(
      h_enc, b_ih, b_hh, b_out, mask0, mask1, skipp, G, out);
}

// Round 6
// 1054.474 us; speedup vs baseline: 9.8944x; 9.8944x over previous
//
#include <hip/hip_runtime.h>

// Decoder GRU, B=128 T=512 X=64 H=256, skip runtime (skip==0 -> generic
// path).  Round 12: register/LDS split residency + explicit occupancy pin.
//
// R10/R11 post-mortems: inline-asm "+v"/"+a" pins do NOT force loop-long
// residency -- the allocator chose a 128-reg budget (R10, targeting
// occupancy it can't use; LDS caps us at 1 WG/CU) or melted down into
// 1.26 GB of scratch traffic (R11, 384 pinned + working > 256 cap).
// The fix is the explicit allocator knob amdgpu_waves_per_eu(2,2)
// (grants a 256-reg budget at our real occupancy: 8 waves = 2/EU) plus a
// resident set that fits comfortably:
//   regs/thread (NT=512, thread = col c=t>>1, k-half kh=t&1):
//     W_hh r,z gates  32 uint4 = 128 regs
//     W_ih 3 gates    12 uint4 =  48 regs
//     W_out            4 uint4 =  16 regs   -> 192 + ~45 working < 256
//   LDS: W_hh n-gate 128 KB ([u][t] uint4; lanes 0-7 of each phase cover
//        all 32 banks -> conflict-free) + state ~23 KB = 151.5 KB.
// Zero weight bytes streamed per step; all fp16 (no accuracy change).
// Floor: 256 dot2/thread + ~90 overhead = ~1400 cyc/step VALU-issue,
// LDS n-gate 128 KB/step ~1030 cyc overlapped -> ~0.6 us/step.
// Structure = R7/R10 verified math: 1-barrier MSTEP + 2-barrier prologue.
typedef _Float16 h2_t __attribute__((ext_vector_type(2)));

constexpr int T_ = 512;
constexpr int X_ = 64;
constexpr int H_ = 256;
constexpr int NWG = 128;  // 1 batch per WG, 1 WG/CU
constexpr int NT = 512;   // 8 waves = 2/EU
constexpr int RS = 16;    // ring slots; lookback 2*skip, OK for skip <= 7

// fp16 weight image in d_ws (uint4 units), all [u][t] with t = threadIdx:
//   u  0..31 : W_hh gates r,z   (g=u>>4, j=u&15; c=t>>1, kh=t&1)
//   u 32..47 : W_hh gate n      (j=u-32)
//   u 48..59 : W_ih 3 gates     (g=(u-48)>>2, j=(u-48)&3)
//   u 60..63 : W_out            (j=u-60; xc=t>>3, sl=t&7)
constexpr int G_TOTAL = 64 * NT;  // 32768 uint4 = 512 KB

__device__ __forceinline__ float sigmoid_f(float x) {
  float e = __expf(fminf(-x, 80.f));
  return 1.f / (1.f + e);
}
__device__ __forceinline__ float tanh_f(float x) {
  float e = __expf(fminf(-2.f * x, 80.f));
  return (1.f - e) / (1.f + e);
}

__device__ __forceinline__ unsigned pk2(float a, float b) {
  h2_t v;
  v[0] = (_Float16)a;
  v[1] = (_Float16)b;
  return __builtin_bit_cast(unsigned, v);
}
__device__ __forceinline__ uint4 pk8(const float* s) {
  return make_uint4(pk2(s[0], s[1]), pk2(s[2], s[3]), pk2(s[4], s[5]),
                    pk2(s[6], s[7]));
}

// fp16-pair dot with fp32 accumulate (v_dot2_f32_f16)
__device__ __forceinline__ float dotp(unsigned w, unsigned h, float acc) {
  h2_t wv = __builtin_bit_cast(h2_t, w);
  h2_t hv = __builtin_bit_cast(h2_t, h);
#if __has_builtin(__builtin_amdgcn_fdot2)
  return __builtin_amdgcn_fdot2(wv, hv, acc, false);
#else
  acc = fmaf((float)wv[0], (float)hv[0], acc);
  return fmaf((float)wv[1], (float)hv[1], acc);
#endif
}
__device__ __forceinline__ float dotq(uint4 w, uint4 h, float acc) {
  acc = dotp(w.x, h.x, acc);
  acc = dotp(w.y, h.y, acc);
  acc = dotp(w.z, h.z, acc);
  acc = dotp(w.w, h.w, acc);
  return acc;
}

// One-time fp32 -> fp16 pack + transpose into register/LDS-friendly layouts.
__global__ void prep_kernel(const float* __restrict__ Wih,
                            const float* __restrict__ Whh,
                            const float* __restrict__ Wout,
                            uint4* __restrict__ G) {
  int id = blockIdx.x * 256 + threadIdx.x;
  if (id >= G_TOTAL) return;
  int t = id & (NT - 1), u = id >> 9;
  int c = t >> 1, kh = t & 1;
  if (u < 32) {  // W_hh r,z
    int g = u >> 4, j = u & 15;
    G[id] = pk8(Whh + (size_t)(g * 256 + c) * H_ + kh * 128 + j * 8);
  } else if (u < 48) {  // W_hh n
    int j = u - 32;
    G[id] = pk8(Whh + (size_t)(512 + c) * H_ + kh * 128 + j * 8);
  } else if (u < 60) {  // W_ih
    int v = u - 48, g = v >> 2, j = v & 3;
    G[id] = pk8(Wih + (size_t)(g * 256 + c) * X_ + kh * 32 + j * 8);
  } else {  // W_out
    int j = u - 60, xc = t >> 3, sl = t & 7;
    G[id] = pk8(Wout + (size_t)xc * H_ + sl * 32 + j * 8);
  }
}

// padded pt2 word index: block (cp>>4) stride 36 words -> PROJ's 8
// sl-address-groups start at disjoint bank quads.
#define PTW(cp) (((cp) >> 4) * 36 + ((cp)&15))

// ---- per-step building blocks (p/q compile-time 0/1 in the main loop) ----

#define GATES(p, i, hn)                                                      \
  float hn;                                                                  \
  {                                                                          \
    float a0 = 0, a1 = 0, z0 = 0, z1 = 0, n0 = 0, n1 = 0, ni = 0;            \
    const uint4* h4 = ((const uint4*)hid2[p]) + kh * 16;                     \
    _Pragma("unroll") for (int j = 0; j < 16; j += 2) {                      \
      uint4 ha = h4[j], hb = h4[j + 1]; /* 2-addr broadcast, free */         \
      uint4 wna = wn4[j * NT + t], wnb = wn4[(j + 1) * NT + t];              \
      a0 = dotq(whh_rz[j], ha, a0);                                          \
      a1 = dotq(whh_rz[j + 1], hb, a1);                                      \
      z0 = dotq(whh_rz[16 + j], ha, z0);                                     \
      z1 = dotq(whh_rz[17 + j], hb, z1);                                     \
      n0 = dotq(wna, ha, n0);                                                \
      n1 = dotq(wnb, hb, n1);                                                \
    }                                                                        \
    const uint4* x4 = ((const uint4*)xt2[p]) + kh * 4;                       \
    _Pragma("unroll") for (int j = 0; j < 4; ++j) {                          \
      uint4 xa = x4[j];                                                      \
      a0 = dotq(wih[j], xa, a0);                                             \
      z0 = dotq(wih[4 + j], xa, z0);                                         \
      ni = dotq(wih[8 + j], xa, ni);                                         \
    }                                                                        \
    float ar = a0 + a1, az = z0 + z1, anh = n0 + n1;                         \
    ar += __shfl_xor(ar, 1);                                                 \
    az += __shfl_xor(az, 1);                                                 \
    anh += __shfl_xor(anh, 1);                                               \
    ni += __shfl_xor(ni, 1);                                                 \
    float r = sigmoid_f(ar + bsr);                                           \
    float z = sigmoid_f(az + bsz);                                           \
    float n = tanh_f(ni + bin_ + r * (anh + bhn_));                          \
    hn = fmaf(z, hid_reg - n, n); /* (1-z)*n + z*hidden */                   \
    if (kh == 0) ring[(i) & (RS - 1)][c] = hn;                               \
  }

#define PROJ(p, q, i)                                                        \
  {                                                                          \
    float fa = 0;                                                            \
    const uint4* p4 = (const uint4*)&pt2[p][sl * 36];                        \
    _Pragma("unroll") for (int j = 0; j < 4; ++j) fa =                       \
        dotq(wout[j], p4[j], fa);                                            \
    fa += __shfl_xor(fa, 1);                                                 \
    fa += __shfl_xor(fa, 2);                                                 \
    fa += __shfl_xor(fa, 4);                                                 \
    float o = fa + bo;                                                       \
    if (sl == 0) out[ob + (size_t)(i)*X_ + xc] = o;                          \
    float oo = __shfl_xor(o, 8);                                             \
    if ((t & 15) == 0) xt2[q][t >> 4] = pk2(o, oo);                          \
  }

// Main-loop step (valid for i >= 2*skip, skip >= 1): pt2[p] was produced at
// step i-1; sg == sp == h(i+1-2*skip) for the next step's hidden/pt.
#define MSTEP(i, p, q)                                                       \
  {                                                                          \
    GATES(p, i, hn)                                                          \
    __builtin_amdgcn_sched_barrier(0);                                       \
    PROJ(p, q, i)                                                            \
    __builtin_amdgcn_sched_barrier(0);                                       \
    if ((i) + 1 < T_) {                                                      \
      float sgp = ring[((i) + 1 - 2 * skip) & (RS - 1)][c];                  \
      float hidn = m0f[(i) + 1] * hn + m1f[(i) + 1] * sgp;                   \
      float ptn = hn + sgp;                                                  \
      hid_reg = hidn;                                                        \
      float ho = __shfl_xor(hidn, 2);                                        \
      float po = __shfl_xor(ptn, 2);                                         \
      if ((t & 3) == 0) {                                                    \
        hid2[q][t >> 2] = pk2(hidn, ho);                                     \
        pt2[q][PTW(t >> 2)] = pk2(ptn, po);                                  \
      }                                                                      \
    }                                                                        \
    __syncthreads();                                                         \
  }

__global__ __attribute__((amdgpu_flat_work_group_size(NT, NT),
                          amdgpu_waves_per_eu(2, 2))) void decoder_kernel(
    const float* __restrict__ h_enc, const float* __restrict__ b_ih,
    const float* __restrict__ b_hh, const float* __restrict__ b_out,
    const int* __restrict__ mask0, const int* __restrict__ mask1,
    const int* __restrict__ skipp, const uint4* __restrict__ G,
    float* __restrict__ out) {
  __shared__ alignas(16) uint4 wn4[16 * NT];       // 128 KB W_hh n-gate [u][t]
  __shared__ float ring[RS][H_];                   // 16 KB h history (fp32)
  __shared__ alignas(16) unsigned hid2[2][H_ / 2]; // fp16 hidden pairs
  __shared__ alignas(16) unsigned pt2[2][8 * 36];  // fp16 h_prev+skip, padded
  __shared__ alignas(16) unsigned xt2[2][X_ / 2];  // fp16 x feedback pairs
  __shared__ float m0f[T_], m1f[T_];               // 4 KB masks
  // total: 131072+16384+1024+2304+256+4096 = 155136 B (151.5 KB)

  const int t = threadIdx.x;
  const int b = blockIdx.x;
  const int c = t >> 1, kh = t & 1;   // gate role: column, k-half
  const int xc = t >> 3, sl = t & 7;  // projection role
  const size_t ob = (size_t)b * T_ * X_;

  // ---- resident weight registers: 48 uint4 = 192 regs/thread ----
  uint4 whh_rz[32];  // r,z gates, 128 k each
  uint4 wih[12];     // 3 gates x 32 k
  uint4 wout[4];     // 32 k-slice of own xc column
#pragma unroll
  for (int u = 0; u < 32; ++u) whh_rz[u] = G[u * NT + t];
#pragma unroll
  for (int u = 0; u < 12; ++u) wih[u] = G[(48 + u) * NT + t];
#pragma unroll
  for (int u = 0; u < 4; ++u) wout[u] = G[(60 + u) * NT + t];

  // ---- LDS: n-gate weights + masks ----
#pragma unroll
  for (int u = 0; u < 16; ++u) wn4[u * NT + t] = G[(32 + u) * NT + t];
  m0f[t] = (float)mask0[t];
  m1f[t] = (float)mask1[t];

  const int skip = skipp[0];
  const int i0 = (skip == 0) ? T_ : ((2 * skip < T_) ? 2 * skip : T_);

  const float bsr = b_ih[c] + b_hh[c];
  const float bsz = b_ih[H_ + c] + b_hh[H_ + c];
  const float bin_ = b_ih[2 * H_ + c];
  const float bhn_ = b_hh[2 * H_ + c];
  const float bo = b_out[xc];

  float hp = h_enc[(size_t)b * H_ + c];
  float hid_reg = (float)mask0[0] * hp;  // hidden(0); skip_g(0) == 0
  float hps_reg = hp;                    // h_prev(0) = h_enc
  {
    float ho = __shfl_xor(hid_reg, 2);
    if ((t & 3) == 0) hid2[0][t >> 2] = pk2(hid_reg, ho);
  }
  if (t < X_ / 2) xt2[0][t] = 0u;  // GO token
  __syncthreads();

  // ---- prologue: generic 2-barrier steps for i < 2*skip ----
  for (int i = 0; i < i0; ++i) {
    const int p = i & 1, q = p ^ 1;
    GATES(p, i, hn)
    {
      int ppos = (i < skip) ? 2 * i + 1 : i - skip;
      bool pz = ppos < skip;
      int pi = ppos - skip;
      if (pi < 0) pi = 0;
      float sp = pz ? 0.f : ((pi == i) ? hn : ring[pi & (RS - 1)][c]);
      float ptv = hps_reg + sp;
      float po = __shfl_xor(ptv, 2);
      if ((t & 3) == 0) pt2[p][PTW(t >> 2)] = pk2(ptv, po);
    }
    if (i + 1 < T_) {
      int i1 = i + 1;
      int pg = (i1 < skip) ? 2 * i1 : i1 - skip;
      bool gz = pg < skip;
      int gi = pg - skip;
      if (gi < 0) gi = 0;
      if (gi >= i1) gz = true;  // unwritten slot == reference zero init
      float sg = gz ? 0.f : ((gi == i) ? hn : ring[gi & (RS - 1)][c]);
      float hidn = m0f[i1] * hn + m1f[i1] * sg;
      hid_reg = hidn;
      float ho = __shfl_xor(hidn, 2);
      if ((t & 3) == 0) hid2[q][t >> 2] = pk2(hidn, ho);
      if (skip > 0 && i1 >= 2 * skip) {  // handoff into fused main loop
        float sgp = ring[(i1 - 2 * skip) & (RS - 1)][c];
        float ptn = hn + sgp;
        float po2 = __shfl_xor(ptn, 2);
        if ((t & 3) == 0) pt2[q][PTW(t >> 2)] = pk2(ptn, po2);
      }
    }
    hps_reg = hn;
    __syncthreads();
    PROJ(p, q, i)
    __syncthreads();
  }

  // ---- main loop: one barrier per step; i0 even so parity is static ----
#pragma unroll 1
  for (int i = i0; i < T_; i += 2) {
    MSTEP(i, 0, 1)
    MSTEP(i + 1, 1, 0)
  }
}

extern "C" void kernel_launch(void* const* d_in, const int* in_sizes, int n_in,
                              void* d_out, int out_size, void* d_ws,
                              size_t ws_size, hipStream_t stream) {
  (void)in_sizes; (void)n_in; (void)out_size; (void)ws_size;
  // d_in[0] = input [B,T,X] — unused by the reference computation.
  const float* h_enc = (const float*)d_in[1];
  const float* W_ih = (const float*)d_in[2];
  const float* W_hh = (const float*)d_in[3];
  const float* b_ih = (const float*)d_in[4];
  const float* b_hh = (const float*)d_in[5];
  const float* W_out = (const float*)d_in[6];
  const float* b_out = (const float*)d_in[7];
  const int* mask0 = (const int*)d_in[8];
  const int* mask1 = (const int*)d_in[9];
  const int* skipp = (const int*)d_in[10];
  float* out = (float*)d_out;
  uint4* G = (uint4*)d_ws;  // 512 KB fp16 weight image

  prep_kernel<<<dim3(G_TOTAL / 256), dim3(256), 0, stream>>>(W_ih, W_hh,
                                                             W_out, G);
  decoder_kernel<<<dim3(NWG), dim3(NT), 0, stream>>>(
      h_enc, b_ih, b_hh, b_out, mask0, mask1, skipp, G, out);
}